// Round 11
// baseline (540.198 us; speedup 1.0000x reference)
//
#include <hip/hip_runtime.h>
#include <math.h>

#define HIDDEN 256
#define NUM_CLASSES 53
#define NWAVES 4
#define BLOCK 256
#define TILE 64
#define XPAD 260      // floats per LDS row (256 + 4 pad); 1040 B, 16B-divisible

// v += dpp_mov(v, CTRL); quad_perm sums
template <int CTRL>
__device__ __forceinline__ float dpp_add(float v) {
    int t = __builtin_amdgcn_update_dpp(0, __float_as_int(v), CTRL, 0xf, 0xf, true);
    return v + __int_as_float(t);
}

__global__ __launch_bounds__(BLOCK, 2) void hattn_tile_kernel(
    const float* __restrict__ x,
    const float* __restrict__ rel_emb0,
    const float* __restrict__ rel_emb1,
    const float* __restrict__ disc,
    const float* __restrict__ bias,
    const int* __restrict__ relation_levels,
    const int* __restrict__ label_index,
    const int* __restrict__ scope,
    float* __restrict__ out)
{
    __shared__ alignas(16) float s_x[TILE][XPAD];       // 66.6 KB
    __shared__ alignas(16) float s_e0[TILE];
    __shared__ alignas(16) float s_e1[TILE];
    __shared__ int2  s_rl[NUM_CLASSES];                 // relation_levels table
    __shared__ int2  s_rlc[TILE];                       // per-row (rl.x, rl.y)
    __shared__ float s_lw[NWAVES];                      // per-wave L partials
    __shared__ alignas(16) float s_rep2[2][2][HIDDEN];  // [lvl][rowhalf][col], 4 KB

    const int tid  = threadIdx.x;
    const int lane = tid & 63;
    const int wave = tid >> 6;          // 0..3

    // one-time: stage relation table; zero s_x (so e=0 * stale is 0*finite, never NaN)
    if (tid < NUM_CLASSES)
        s_rl[tid] = *reinterpret_cast<const int2*>(relation_levels + 2 * tid);
    {
        float4 z = make_float4(0.f, 0.f, 0.f, 0.f);
        float* base = &s_x[0][0];
        const int nf4 = (TILE * XPAD) / 4;              // 4160
        for (int i = tid; i < nf4; i += BLOCK)
            *reinterpret_cast<float4*>(base + 4 * i) = z;
    }

    const int bag   = blockIdx.x;
    const int start = scope[bag];
    const int end   = scope[bag + 1];

    // phase-A mapping: 4 lanes per row
    const int arow = tid >> 2;          // 0..63
    const int q    = tid & 3;

    // phase-B mapping: wave -> (level, row-half); lane -> 4 columns
    const int lvl     = wave >> 1;
    const int rowhalf = wave & 1;

    float4 oacc = make_float4(0.f, 0.f, 0.f, 0.f);
    float  lacc = 0.f;

    __syncthreads();

    for (int ts = start; ts < end; ts += TILE) {
        // ---- stage: x rows (skip out-of-bag rows -> no over-fetch) + labels ----
        #pragma unroll 4
        for (int j = 0; j < 16; ++j) {
            const int r  = 4 * j + wave;                 // wave-uniform row
            const int rg = ts + r;
            if (rg < end) {                              // scalar branch
                const float4 v = *reinterpret_cast<const float4*>(
                    x + ((size_t)rg << 8) + (lane << 2));
                *reinterpret_cast<float4*>(&s_x[r][lane << 2]) = v;
            }
        }
        if (tid < TILE && ts + tid < end) {
            const int lb = label_index[ts + tid];
            s_rlc[tid] = s_rl[lb];
        }
        __syncthreads();

        // ---- phase A: per-row dots (4 lanes/row, 64 cols each) -> e ----
        if (ts + arow < end) {
            const int2 rl = s_rlc[arow];                 // quad-broadcast
            const float* c0 = rel_emb0 + ((size_t)rl.x << 8) + (q << 6);
            const float* c1 = rel_emb1 + ((size_t)rl.y << 8) + (q << 6);
            const float* xr = &s_x[arow][q << 6];
            float p0 = 0.f, p1 = 0.f;
            #pragma unroll 4
            for (int i = 0; i < 16; ++i) {
                const float4 xv = *reinterpret_cast<const float4*>(xr + 4 * i);
                const float4 a0 = *reinterpret_cast<const float4*>(c0 + 4 * i);
                const float4 a1 = *reinterpret_cast<const float4*>(c1 + 4 * i);
                p0 += xv.x*a0.x + xv.y*a0.y + xv.z*a0.z + xv.w*a0.w;
                p1 += xv.x*a1.x + xv.y*a1.y + xv.z*a1.z + xv.w*a1.w;
            }
            p0 = dpp_add<0xB1>(p0); p0 = dpp_add<0x4E>(p0);   // quad sum
            p1 = dpp_add<0xB1>(p1); p1 = dpp_add<0x4E>(p1);
            if (q == 0) { s_e0[arow] = __expf(p0); s_e1[arow] = __expf(p1); }
        } else if (q == 0) {
            s_e0[arow] = 0.f; s_e1[arow] = 0.f;
        }
        __syncthreads();

        // ---- phase B: weighted column sums; wave covers (lvl, 32 rows), lane = 4 cols ----
        {
            const int   rbase = rowhalf << 5;            // 0 or 32
            const float* eb   = lvl ? s_e1 : s_e0;
            #pragma unroll
            for (int g = 0; g < 8; ++g) {
                const int r0 = rbase + 4 * g;
                const float4 e4 = *reinterpret_cast<const float4*>(&eb[r0]); // broadcast
                #pragma unroll
                for (int k = 0; k < 4; ++k) {
                    const float e = (k == 0) ? e4.x : (k == 1) ? e4.y : (k == 2) ? e4.z : e4.w;
                    const float4 xv = *reinterpret_cast<const float4*>(&s_x[r0 + k][lane << 2]);
                    oacc.x += e * xv.x; oacc.y += e * xv.y;
                    oacc.z += e * xv.z; oacc.w += e * xv.w;
                    lacc += e;
                }
            }
        }
        __syncthreads();   // B done before next stage overwrites s_x
    }

    // ---- merge: stash per-wave accumulators, then class epilogue ----
    *reinterpret_cast<float4*>(&s_rep2[lvl][rowhalf][lane << 2]) = oacc;
    if (lane == 0) s_lw[wave] = lacc;
    __syncthreads();

    const float L0 = s_lw[0] + s_lw[1];
    const float L1 = s_lw[2] + s_lw[3];
    const float i0 = (L0 > 0.f) ? 1.f / L0 : 0.f;
    const float i1 = (L1 > 0.f) ? 1.f / L1 : 0.f;

    const int c  = tid >> 2;
    const int l4 = tid & 3;
    if (c < NUM_CLASSES) {
        const float4* dr  = reinterpret_cast<const float4*>(disc + (size_t)c * (2 * HIDDEN));
        const float4* r00 = reinterpret_cast<const float4*>(&s_rep2[0][0][0]);
        const float4* r01 = reinterpret_cast<const float4*>(&s_rep2[0][1][0]);
        const float4* r10 = reinterpret_cast<const float4*>(&s_rep2[1][0][0]);
        const float4* r11 = reinterpret_cast<const float4*>(&s_rep2[1][1][0]);
        float pH0 = 0.f, pH1 = 0.f;
        #pragma unroll
        for (int i = 0; i < 16; ++i) {
            const int idx = l4 + 4 * i;                  // f4 index within level
            const float4 a = r00[idx], b = r01[idx], d = dr[idx];
            pH0 += (a.x + b.x) * d.x + (a.y + b.y) * d.y
                 + (a.z + b.z) * d.z + (a.w + b.w) * d.w;
        }
        #pragma unroll
        for (int i = 0; i < 16; ++i) {
            const int idx = l4 + 4 * i;
            const float4 a = r10[idx], b = r11[idx], d = dr[64 + idx];
            pH1 += (a.x + b.x) * d.x + (a.y + b.y) * d.y
                 + (a.z + b.z) * d.z + (a.w + b.w) * d.w;
        }
        float p = pH0 * i0 + pH1 * i1;
        p = dpp_add<0xB1>(p);   // quad reduce
        p = dpp_add<0x4E>(p);
        if (l4 == 0) out[bag * NUM_CLASSES + c] = p + bias[c];
    }
}

extern "C" void kernel_launch(void* const* d_in, const int* in_sizes, int n_in,
                              void* d_out, int out_size, void* d_ws, size_t ws_size,
                              hipStream_t stream) {
    const float* x               = (const float*)d_in[0];
    const float* rel_emb0        = (const float*)d_in[1];
    const float* rel_emb1        = (const float*)d_in[2];
    const float* disc            = (const float*)d_in[3];
    const float* bias            = (const float*)d_in[4];
    const int*   relation_levels = (const int*)d_in[5];
    const int*   label_index     = (const int*)d_in[6];
    const int*   scope           = (const int*)d_in[7];
    float*       out             = (float*)d_out;

    const int n_bags = in_sizes[7] - 1;   // 4096

    // single unconditional path: no workspace dependency
    hattn_tile_kernel<<<n_bags, BLOCK, 0, stream>>>(
        x, rel_emb0, rel_emb1, disc, bias,
        relation_levels, label_index, scope, out);
}